// Round 14
// baseline (102.745 us; speedup 1.0000x reference)
//
#include <hip/hip_runtime.h>
#include <math.h>

#define NH 16
#define DPH 64
#define SLEN 2048
#define BSZ 2
#define DIM 1024
#define NTOK (BSZ * SLEN)
#define LOG2E 1.44269504088896f

typedef unsigned short ushortT;
typedef __attribute__((ext_vector_type(8))) short short8;
typedef __attribute__((ext_vector_type(4))) float f32x4;

typedef __attribute__((address_space(1))) const unsigned int gu32c;
typedef __attribute__((address_space(3))) unsigned int lu32;

__device__ __forceinline__ void gld16(const void* g, void* l) {
    __builtin_amdgcn_global_load_lds((gu32c*)g, (lu32*)l, 16, 0, 0);
}

__device__ __forceinline__ ushortT f2bf(float f) {
    unsigned int u = __builtin_bit_cast(unsigned int, f);
    u = u + 0x7fffu + ((u >> 16) & 1u);  // RNE
    return (ushortT)(u >> 16);
}

__device__ __forceinline__ unsigned int cvtpk_bf16(float a, float b) {
    unsigned int r;
    asm("v_cvt_pk_bf16_f32 %0, %1, %2" : "=v"(r) : "v"(a), "v"(b));
    return r;  // lo = bf16(a), hi = bf16(b), RNE
}

// ---------------------------------------------------------------------------
// Fused prep: blocks [0,2048): x fp32->bf16 (8/thread);
//             blocks [2048,3072): W[k][n] -> Wt[n][k] bf16, 64x64 tiles.
// ---------------------------------------------------------------------------
__global__ __launch_bounds__(256) void cvt_all(const float* __restrict__ x,
                                               ushortT* __restrict__ xb,
                                               const float* __restrict__ W0, const float* __restrict__ W1,
                                               const float* __restrict__ W2, const float* __restrict__ W3,
                                               ushortT* __restrict__ T0, ushortT* __restrict__ T1,
                                               ushortT* __restrict__ T2, ushortT* __restrict__ T3) {
    __shared__ float tile[64][65];
    const int tid = threadIdx.x;
    const int bid = blockIdx.x;
    if (bid < 2048) {
        size_t i = (size_t)bid * 256 + tid;
        float4 a = *(const float4*)&x[i * 8];
        float4 b = *(const float4*)&x[i * 8 + 4];
        short8 v;
        v[0] = (short)f2bf(a.x); v[1] = (short)f2bf(a.y);
        v[2] = (short)f2bf(a.z); v[3] = (short)f2bf(a.w);
        v[4] = (short)f2bf(b.x); v[5] = (short)f2bf(b.y);
        v[6] = (short)f2bf(b.z); v[7] = (short)f2bf(b.w);
        *(short8*)&xb[i * 8] = v;
        return;
    }
    const int widx = bid - 2048;
    const int z = widx >> 8, rem = widx & 255;
    const float* W = z == 0 ? W0 : z == 1 ? W1 : z == 2 ? W2 : W3;
    ushortT* T = z == 0 ? T0 : z == 1 ? T1 : z == 2 ? T2 : T3;
    const int kb = (rem >> 4) * 64, nb = (rem & 15) * 64;
#pragma unroll
    for (int it = 0; it < 4; it++) {
        int chunk = it * 256 + tid;
        int r = chunk >> 4, c4 = (chunk & 15) * 4;
        *(float4*)&tile[r][c4] = *(const float4*)&W[(size_t)(kb + r) * DIM + nb + c4];
    }
    __syncthreads();
#pragma unroll
    for (int it = 0; it < 2; it++) {
        int chunk = it * 256 + tid;
        int n = chunk >> 3, k8 = (chunk & 7) * 8;
        short8 o;
#pragma unroll
        for (int j = 0; j < 8; j++) o[j] = (short)f2bf(tile[k8 + j][n]);
        *(short8*)&T[(size_t)(nb + n) * DIM + kb + k8] = o;
    }
}

// ---------------------------------------------------------------------------
// Fused QKV GEMM, 8-wave (512 thr) 128x256 tile, BK=32 phases, ring-3
// half-slots: A 3x[128][32] (24KB) + B 3x[256][32] (48KB) = 72KB LDS ->
// TWO blocks/CU co-resident (decoupled barriers = cross-block overlap).
// Per phase p: read slot p%3 (staged at p-2), stage slot (p+2)%3, 16 MFMA.
// vmcnt(3) steady (6 outstanding, drain oldest 3), vmcnt(0) at last phase.
// Wave tile 64x64 = 1 head slab -> same fused epilogue as R12/R13.
// Grid 32x12 = 384 blocks (1.5/CU), XCD-bijective swizzle.
// ---------------------------------------------------------------------------
__global__ __launch_bounds__(512, 2) void gemm_qkv8(const ushortT* __restrict__ A,
                                                    const ushortT* __restrict__ Bt,
                                                    const float* __restrict__ bq,
                                                    const float* __restrict__ bk,
                                                    const float* __restrict__ bv,
                                                    const float* __restrict__ ascale,
                                                    ushortT* __restrict__ Qb,
                                                    ushortT* __restrict__ Kb,
                                                    ushortT* __restrict__ VF) {
    __shared__ __align__(16) ushortT lds[36864];  // 72 KiB: A 3x4096, B 3x8192 @12288
    const int tid = threadIdx.x;
    const int lane = tid & 63, wid = tid >> 6;    // 8 waves
    const int wm = wid >> 2, wn = wid & 3;        // 2 x 4 waves, wave tile 64x64
    const int lo = lane & 15, hi = lane >> 4;
    const int bid = blockIdx.x;
    const int swz = (bid & 7) * 48 + (bid >> 3);  // XCD-bijective (384 % 8 == 0)
    const int bx = swz % 12, by = swz / 12;
    const int row0 = by * 128, col0 = bx * 256;
    const int srow = tid >> 2, sc = tid & 3;      // 512 thr: [128 rows][4 chunks]
    f32x4 acc[4][4] = {};
    short8 af[4], bfr[4];

    auto stage = [&](int slot, int p) {  // one k-half of tile p>>1
        const int kt = p >> 1, ksh = p & 1;
        const int koff = kt * 64 + ksh * 32;
        {   // A slot: [128][32] = 8KB, 1 gld16/thread
            int gch = sc ^ ((srow >> 1) & 3);
            gld16(&A[(size_t)(row0 + srow) * DIM + koff + gch * 8],
                  &lds[slot * 4096 + tid * 8]);
        }
#pragma unroll
        for (int r = 0; r < 2; r++) {  // B slot: [256][32] = 16KB, 2 gld16/thread
            int row = r * 128 + srow;
            int gch = sc ^ ((row >> 1) & 3);
            gld16(&Bt[(size_t)(col0 + row) * DIM + koff + gch * 8],
                  &lds[12288 + slot * 8192 + (r * 512 + tid) * 8]);
        }
    };
    auto loadA = [&](int slot) {
        int base = slot * 4096;
#pragma unroll
        for (int mm = 0; mm < 4; mm++) {
            int row = wm * 64 + mm * 16 + lo;
            af[mm] = *(const short8*)&lds[base + row * 32 + (hi ^ ((row >> 1) & 3)) * 8];
        }
    };
    auto loadB = [&](int slot) {
        int base = 12288 + slot * 8192;
#pragma unroll
        for (int n = 0; n < 4; n++) {
            int row = wn * 64 + n * 16 + lo;
            bfr[n] = *(const short8*)&lds[base + row * 32 + (hi ^ ((row >> 1) & 3)) * 8];
        }
    };
    auto mfma16 = [&]() {
        __builtin_amdgcn_s_setprio(1);
#pragma unroll
        for (int mm = 0; mm < 4; mm++)
#pragma unroll
            for (int n = 0; n < 4; n++)
                acc[mm][n] = __builtin_amdgcn_mfma_f32_16x16x32_bf16(
                    af[mm], bfr[n], acc[mm][n], 0, 0, 0);
        __builtin_amdgcn_s_setprio(0);
    };

    // prologue: phases 0,1 into slots 0,1 (6 loads/thread outstanding)
    stage(0, 0); stage(1, 1);

#pragma unroll 1
    for (int p = 0; p < 32; ++p) {
        if (p < 31) { asm volatile("s_waitcnt vmcnt(3)" ::: "memory"); }
        else        { asm volatile("s_waitcnt vmcnt(0)" ::: "memory"); }
        asm volatile("s_barrier" ::: "memory");
        const int slot = p % 3;
        loadA(slot); loadB(slot);
        if (p < 30) stage((p + 2) % 3, p + 2);
        mfma16();
    }
    __syncthreads();  // staging LDS now dead

    // ---- epilogue: wave tile = 64 tokens x 64 d (one head slab) ----
    const int cg = col0 + wn * 64;
    const int which = cg >> 10;  // 0=Q 1=K 2=V (tile never straddles)
    const int cwin = cg & 1023;
    const int h = cwin >> 6;
    const int t0g = row0 + wm * 64;
    const int b = t0g >> 11, tok0 = t0g & (SLEN - 1);
    const float* bias = which == 0 ? bq : which == 1 ? bk : bv;

    float bb4[4];
#pragma unroll
    for (int n = 0; n < 4; n++) bb4[n] = bias[cwin + n * 16 + lo];
#pragma unroll
    for (int m = 0; m < 4; m++)
#pragma unroll
        for (int n = 0; n < 4; n++)
#pragma unroll
            for (int r = 0; r < 4; r++) acc[m][n][r] += bb4[n];

    if (which < 2) {  // fused L2 norm over the 64-wide head row
        float asc = (which == 0) ? ascale[0] * LOG2E : 1.0f;
#pragma unroll
        for (int m = 0; m < 4; m++)
#pragma unroll
            for (int r = 0; r < 4; r++) {
                float ss = acc[m][0][r] * acc[m][0][r] + acc[m][1][r] * acc[m][1][r] +
                           acc[m][2][r] * acc[m][2][r] + acc[m][3][r] * acc[m][3][r];
#pragma unroll
                for (int o = 8; o > 0; o >>= 1) ss += __shfl_xor(ss, o);
                float sc2 = asc / fmaxf(sqrtf(ss), 1e-12f);
#pragma unroll
                for (int n = 0; n < 4; n++) acc[m][n][r] *= sc2;
            }
    }

    ushortT* tl = &lds[wid * 4096];  // wave-private 8KB bounce ([64][64] bf16)
    if (which < 2) {
#pragma unroll
        for (int m = 0; m < 4; m++)
#pragma unroll
            for (int n = 0; n < 4; n++)
#pragma unroll
                for (int r = 0; r < 4; r++) {
                    int row = m * 16 + 4 * hi + r;
                    int c = n * 2 + (lo >> 3);
                    tl[row * 64 + ((c ^ (row & 7)) << 3) + (lo & 7)] = f2bf(acc[m][n][r]);
                }
        ushortT* op = which == 0 ? Qb : Kb;
        const size_t base = ((size_t)(b * NH + h) * SLEN + tok0) * DPH;
#pragma unroll
        for (int j = 0; j < 8; j++) {
            int cid = j * 64 + lane;  // 512 16B chunks: row-major [64][8]
            int rowL = cid >> 3, c = cid & 7;
            uint4 v = *(const uint4*)&tl[rowL * 64 + ((c ^ (rowL & 7)) << 3)];
            *(uint4*)&op[base + (size_t)cid * 8] = v;
        }
    } else {
#pragma unroll
        for (int m = 0; m < 4; m++)
#pragma unroll
            for (int n = 0; n < 4; n++)
#pragma unroll
                for (int r = 0; r < 4; r++) {
                    int row = m * 16 + 4 * hi + r;
                    int c = n * 2 + (lo >> 3);
                    tl[row * 64 + ((c ^ ((row >> 3) & 7)) << 3) + (lo & 7)] = f2bf(acc[m][n][r]);
                }
        const int bh = b * NH + h;
        const int kt = tok0 >> 6;  // wave covers exactly one key tile
#pragma unroll
        for (int c2i = 0; c2i < 8; c2i++) {
            int jd = c2i >> 1, ks2 = c2i & 1;
            int colL = jd * 16 + lo;
            int cc2 = colL >> 3;
            short8 v;
#pragma unroll
            for (int e = 0; e < 8; e++) {
                int rowL = ks2 * 32 + 8 * hi + e;
                v[e] = (short)tl[rowL * 64 + ((cc2 ^ ((rowL >> 3) & 7)) << 3) + (colL & 7)];
            }
            *(short8*)&VF[((size_t)bh * 32 + kt) * 4096 + (size_t)(c2i * 64 + lane) * 8] = v;
        }
    }
}

// ---------------------------------------------------------------------------
// O-projection: out = ctx(4096,1024)bf16 @ Wo^T + bo, fp32 out.
// 512 thr / 8 waves, 128x128 tile, half-slot ring, vmcnt(4) steady,
// tail 2/0. LDS 64 KB -> 2 blocks/CU. Grid 256, XCD-swizzled. (R11)
// ---------------------------------------------------------------------------
__global__ __launch_bounds__(512, 2) void gemm_oproj(const ushortT* __restrict__ A,
                                                     const ushortT* __restrict__ Bt,
                                                     const float* __restrict__ bias,
                                                     float* __restrict__ outF) {
    __shared__ __align__(16) ushortT lds[32768];  // 64 KiB
    const int tid = threadIdx.x;
    const int lane = tid & 63, wid = tid >> 6;
    const int wm = wid >> 2, wn = wid & 3;  // 2 x 4 waves; wave tile 64 x 32
    const int lo = lane & 15, hi = lane >> 4;
    const int bid = blockIdx.x;
    const int swz = (bid & 7) * 32 + (bid >> 3);  // 256 % 8 == 0
    const int bx = swz & 7, by = swz >> 3;
    const int row0 = by * 128, col0 = bx * 128;
    const int srow = tid >> 2, sc = tid & 3;
    f32x4 acc[4][2] = {};
    short8 afO[2], bfO[2];

    auto stage = [&](int isA, int buf, int ksh, int kt) {
        const ushortT* g = isA ? A : Bt;
        int r0 = isA ? row0 : col0;
        int base = (isA ? 0 : 16384) + (buf * 2 + ksh) * 4096;
        int gch = sc ^ ((srow >> 1) & 3);
        gld16(&g[(size_t)(r0 + srow) * DIM + kt * 64 + ksh * 32 + gch * 8],
              &lds[base + tid * 8]);
    };
    auto loadAO = [&](int buf, int ks, int mh) {
        int base = (buf * 2 + ks) * 4096;
#pragma unroll
        for (int mm = 0; mm < 2; mm++) {
            int row = wm * 64 + (mh * 2 + mm) * 16 + lo;
            afO[mm] = *(const short8*)&lds[base + row * 32 + (hi ^ ((row >> 1) & 3)) * 8];
        }
    };
    auto loadBO = [&](int buf, int ks) {
        int base = 16384 + (buf * 2 + ks) * 4096;
#pragma unroll
        for (int n = 0; n < 2; n++) {
            int row = wn * 32 + n * 16 + lo;
            bfO[n] = *(const short8*)&lds[base + row * 32 + (hi ^ ((row >> 1) & 3)) * 8];
        }
    };
    auto mfma4 = [&](int mh) {
        __builtin_amdgcn_s_setprio(1);
#pragma unroll
        for (int mm = 0; mm < 2; mm++)
#pragma unroll
            for (int n = 0; n < 2; n++)
                acc[mh * 2 + mm][n] = __builtin_amdgcn_mfma_f32_16x16x32_bf16(
                    afO[mm], bfO[n], acc[mh * 2 + mm][n], 0, 0, 0);
        __builtin_amdgcn_s_setprio(0);
    };

    stage(1, 0, 0, 0); stage(0, 0, 0, 0);
    stage(1, 0, 1, 0); stage(0, 0, 1, 0);
    stage(1, 1, 0, 1); stage(0, 1, 0, 1);

#pragma unroll 1
    for (int it = 0; it < 8; ++it) {
        const int o = it * 2 + 1;
        const bool more = (it < 7);
        asm volatile("s_waitcnt vmcnt(4)" ::: "memory");
        asm volatile("s_barrier" ::: "memory");
        loadAO(0, 0, 0); loadBO(0, 0);
        stage(1, 1, 1, o);
        mfma4(0);
        asm volatile("s_barrier" ::: "memory");
        loadAO(0, 0, 1);
        stage(0, 1, 1, o);
        mfma4(1);
        asm volatile("s_waitcnt vmcnt(4)" ::: "memory");
        asm volatile("s_barrier" ::: "memory");
        loadAO(0, 1, 0); loadBO(0, 1);
        if (more) stage(1, 0, 0, o + 1);
        mfma4(0);
        asm volatile("s_barrier" ::: "memory");
        loadAO(0, 1, 1);
        if (more) stage(0, 0, 0, o + 1);
        mfma4(1);
        if (more) { asm volatile("s_waitcnt vmcnt(4)" ::: "memory"); }
        else      { asm volatile("s_waitcnt vmcnt(2)" ::: "memory"); }
        asm volatile("s_barrier" ::: "memory");
        loadAO(1, 0, 0); loadBO(1, 0);
        if (more) stage(1, 0, 1, o + 1);
        mfma4(0);
        asm volatile("s_barrier" ::: "memory");
        loadAO(1, 0, 1);
        if (more) stage(0, 0, 1, o + 1);
        mfma4(1);
        if (more) { asm volatile("s_waitcnt vmcnt(4)" ::: "memory"); }
        else      { asm volatile("s_waitcnt vmcnt(0)" ::: "memory"); }
        asm volatile("s_barrier" ::: "memory");
        loadAO(1, 1, 0); loadBO(1, 1);
        if (more) stage(1, 1, 0, o + 2);
        mfma4(0);
        asm volatile("s_barrier" ::: "memory");
        loadAO(1, 1, 1);
        if (more) stage(0, 1, 0, o + 2);
        mfma4(1);
    }
    __syncthreads();  // staging LDS dead

    float bb[2];
#pragma unroll
    for (int n = 0; n < 2; n++) bb[n] = bias[col0 + wn * 32 + n * 16 + lo];
#pragma unroll
    for (int m = 0; m < 4; m++)
#pragma unroll
        for (int n = 0; n < 2; n++)
#pragma unroll
            for (int r = 0; r < 4; r++) acc[m][n][r] += bb[n];

    float* tl = (float*)&lds[wid * 4096];  // wave-private [64][32] fp32, 8KB
#pragma unroll
    for (int m = 0; m < 4; m++)
#pragma unroll
        for (int n = 0; n < 2; n++)
#pragma unroll
            for (int r = 0; r < 4; r++) {
                int row = m * 16 + hi * 4 + r;
                int col = n * 16 + lo;
                int cc = col >> 2;
                tl[row * 32 + ((cc ^ (row & 7)) << 2) + (col & 3)] = acc[m][n][r];
            }
#pragma unroll
    for (int j = 0; j < 8; j++) {
        int cid = j * 64 + lane;  // 512 16B chunks: [64 rows][8 cc]
        int rowR = cid >> 3, cc = cid & 7;
        f32x4 v = *(const f32x4*)&tl[rowR * 32 + ((cc ^ (rowR & 7)) << 2)];
        int rg = row0 + wm * 64 + rowR;
        int cgl = col0 + wn * 32 + cc * 4;
        *(f32x4*)&outF[(size_t)rg * DIM + cgl] = v;
    }
}

// ---------------------------------------------------------------------------
// Causal flash attention, swapped-QK^T, exact fixed-shift exp2 softmax.
// R11 version: Ks double-buffered (one barrier per key tile), cvt_pk P->bf16,
// setprio around MFMA clusters. LDS 32 KB.
// ---------------------------------------------------------------------------
__global__ __launch_bounds__(512, 4) void attn(const ushortT* __restrict__ Q,
                                               const ushortT* __restrict__ K,
                                               const ushortT* __restrict__ VF,
                                               const float* __restrict__ scale,
                                               ushortT* __restrict__ ctx) {
    __shared__ __align__(16) ushortT Ks[2][64 * 64];
    __shared__ __align__(16) ushortT Ps[8 * 16 * 64];
    const int tid = threadIdx.x, lane = tid & 63, wid = tid >> 6;
    const int wg = wid & 3, sg = wid >> 2;
    const int bh = blockIdx.x, p = blockIdx.y;
    const int qt = sg ? p : 31 - p;
    const int kbmax = 31 - p;
    const size_t hb = (size_t)bh * SLEN * DPH;
    const int lo = lane & 15, hi = lane >> 4;
    const float mshift = fabsf(scale[0]) * LOG2E;

    short8 aq[2];
    {
        const int qrow = qt * 64 + wg * 16 + lo;
#pragma unroll
        for (int ks = 0; ks < 2; ks++)
            aq[ks] = *(const short8*)&Q[hb + (size_t)qrow * DPH + ks * 32 + 8 * hi];
    }

    const int srow = tid >> 3, sslot = tid & 7;
    const int sldsoff = srow * 64 + ((sslot ^ (srow & 7)) << 3);
    uint4 kr = *(const uint4*)&K[hb + (size_t)srow * DPH + sslot * 8];
    *(uint4*)&Ks[0][sldsoff] = kr;
    __syncthreads();

    f32x4 accd[4] = {};
    float lp = 0.f;

    for (int kb = 0; kb <= kbmax; kb++) {
        const int cur = kb & 1;
        if (kb < kbmax)
            kr = *(const uint4*)&K[hb + (size_t)((kb + 1) * 64 + srow) * DPH + sslot * 8];

        if (kb <= qt) {
            short8 bv[8];
            const ushortT* vt = &VF[(((size_t)bh * 32 + kb) * 512 + lane) * 8];
#pragma unroll
            for (int c = 0; c < 8; c++) bv[c] = *(const short8*)&vt[(size_t)c * 512];

            f32x4 sf[4] = {};
            __builtin_amdgcn_s_setprio(1);
#pragma unroll
            for (int ks = 0; ks < 2; ks++)
#pragma unroll
                for (int j = 0; j < 4; j++) {
                    int row = j * 16 + lo;
                    short8 bk = *(const short8*)&Ks[cur][row * 64 + (((ks * 4 + hi) ^ (row & 7)) << 3)];
                    sf[j] = __builtin_amdgcn_mfma_f32_16x16x32_bf16(bk, aq[ks], sf[j], 0, 0, 0);
                }
            __builtin_amdgcn_s_setprio(0);

            if (kb == qt) {
#pragma unroll
                for (int j = 0; j < 4; j++)
#pragma unroll
                    for (int r = 0; r < 4; r++)
                        if (j * 16 + 4 * hi + r > wg * 16 + lo) sf[j][r] = -INFINITY;
            }

#pragma unroll
            for (int j = 0; j < 4; j++) {
                float pv0 = __builtin_amdgcn_exp2f(sf[j][0] - mshift);
                float pv1 = __builtin_amdgcn_exp2f(sf[j][1] - mshift);
                float pv2 = __builtin_amdgcn_exp2f(sf[j][2] - mshift);
                float pv3 = __builtin_amdgcn_exp2f(sf[j][3] - mshift);
                lp += (pv0 + pv1) + (pv2 + pv3);
                uint2 pk;
                pk.x = cvtpk_bf16(pv0, pv1);
                pk.y = cvtpk_bf16(pv2, pv3);
                int slot = (4 * j + hi) ^ (2 * (lo & 7));
                *(uint2*)&Ps[wid * 1024 + lo * 64 + slot * 4] = pk;
            }

            __builtin_amdgcn_s_setprio(1);
#pragma unroll
            for (int ks = 0; ks < 2; ks++) {
                int slot0 = (8 * ks + 2 * hi) ^ (2 * (lo & 7));
                short8 ap = *(const short8*)&Ps[wid * 1024 + lo * 64 + slot0 * 4];
#pragma unroll
                for (int jd = 0; jd < 4; jd++)
                    accd[jd] = __builtin_amdgcn_mfma_f32_16x16x32_bf16(ap, bv[jd * 2 + ks], accd[jd], 0, 0, 0);
            }
            __builtin_amdgcn_s_setprio(0);
        }

        if (kb < kbmax) *(uint4*)&Ks[cur ^ 1][sldsoff] = kr;
        __syncthreads();  // one barrier per tile: next tile's buffer ready
    }

    lp += __shfl_xor(lp, 16);
    lp += __shfl_xor(lp, 32);

    const int b = bh >> 4, h = bh & 15;
#pragma unroll
    for (int r = 0; r < 4; r++) {
        float lr = __shfl(lp, (lane & 48) | (4 * hi + r));
        float inv = 1.0f / lr;
        int t = qt * 64 + wg * 16 + 4 * hi + r;
#pragma unroll
        for (int jd = 0; jd < 4; jd++) {
            int d = jd * 16 + lo;
            ctx[(size_t)(b * SLEN + t) * DIM + h * 64 + d] = f2bf(accd[jd][r] * inv);
        }
    }
}

// ---------------------------------------------------------------------------
// inputs: 0 x, 1 mask(unused), 2 Wq, 3 bq, 4 Wk, 5 bk, 6 Wv, 7 bv, 8 Wo,
// 9 bo, 10 attention_scale
// ---------------------------------------------------------------------------
extern "C" void kernel_launch(void* const* d_in, const int* in_sizes, int n_in,
                              void* d_out, int out_size, void* d_ws,
                              size_t ws_size, hipStream_t stream) {
    const float* x = (const float*)d_in[0];
    const float* Wq = (const float*)d_in[2];
    const float* bq = (const float*)d_in[3];
    const float* Wk = (const float*)d_in[4];
    const float* bk = (const float*)d_in[5];
    const float* Wv = (const float*)d_in[6];
    const float* bv = (const float*)d_in[7];
    const float* Wo = (const float*)d_in[8];
    const float* bo = (const float*)d_in[9];
    const float* ascale = (const float*)d_in[10];
    float* outF = (float*)d_out;

    unsigned char* ws = (unsigned char*)d_ws;
    const size_t MB = 1u << 20;
    ushortT* xb = (ushortT*)(ws);               // 8 MB
    ushortT* Wqkvt = (ushortT*)(ws + 8 * MB);   // 6 MB
    ushortT* Wot = (ushortT*)(ws + 14 * MB);    // 2 MB
    ushortT* Qb = (ushortT*)(ws + 16 * MB);     // 8 MB
    ushortT* Kb = (ushortT*)(ws + 24 * MB);     // 8 MB
    ushortT* VFb = (ushortT*)(ws + 32 * MB);    // 8 MB
    ushortT* ctxb = (ushortT*)(ws + 40 * MB);   // 8 MB; total 48 MB

    cvt_all<<<3072, 256, 0, stream>>>(x, xb, Wq, Wk, Wv, Wo, Wqkvt,
                                      Wqkvt + (size_t)1024 * 1024,
                                      Wqkvt + (size_t)2048 * 1024, Wot);

    gemm_qkv8<<<dim3(384), 512, 0, stream>>>(xb, Wqkvt, bq, bk, bv, ascale, Qb, Kb, VFb);

    attn<<<dim3(32, 16), 512, 0, stream>>>(Qb, Kb, VFb, ascale, ctxb);

    gemm_oproj<<<dim3(256), 512, 0, stream>>>(ctxb, Wot, bo, outF);
}

// Round 15
// 91.316 us; speedup vs baseline: 1.1252x; 1.1252x over previous
//
#include <hip/hip_runtime.h>
#include <math.h>

#define NH 16
#define DPH 64
#define SLEN 2048
#define BSZ 2
#define DIM 1024
#define NTOK (BSZ * SLEN)
#define LOG2E 1.44269504088896f

typedef unsigned short ushortT;
typedef __attribute__((ext_vector_type(8))) short short8;
typedef __attribute__((ext_vector_type(4))) float f32x4;

typedef __attribute__((address_space(1))) const unsigned int gu32c;
typedef __attribute__((address_space(3))) unsigned int lu32;

__device__ __forceinline__ void gld16(const void* g, void* l) {
    __builtin_amdgcn_global_load_lds((gu32c*)g, (lu32*)l, 16, 0, 0);
}

__device__ __forceinline__ ushortT f2bf(float f) {
    unsigned int u = __builtin_bit_cast(unsigned int, f);
    u = u + 0x7fffu + ((u >> 16) & 1u);  // RNE
    return (ushortT)(u >> 16);
}

__device__ __forceinline__ unsigned int cvtpk_bf16(float a, float b) {
    unsigned int r;
    asm("v_cvt_pk_bf16_f32 %0, %1, %2" : "=v"(r) : "v"(a), "v"(b));
    return r;  // lo = bf16(a), hi = bf16(b), RNE
}

// ---------------------------------------------------------------------------
// Fused prep: blocks [0,2048): x fp32->bf16 (8/thread);
//             blocks [2048,3072): W[k][n] -> Wt[n][k] bf16, 64x64 tiles.
// ---------------------------------------------------------------------------
__global__ __launch_bounds__(256) void cvt_all(const float* __restrict__ x,
                                               ushortT* __restrict__ xb,
                                               const float* __restrict__ W0, const float* __restrict__ W1,
                                               const float* __restrict__ W2, const float* __restrict__ W3,
                                               ushortT* __restrict__ T0, ushortT* __restrict__ T1,
                                               ushortT* __restrict__ T2, ushortT* __restrict__ T3) {
    __shared__ float tile[64][65];
    const int tid = threadIdx.x;
    const int bid = blockIdx.x;
    if (bid < 2048) {
        size_t i = (size_t)bid * 256 + tid;
        float4 a = *(const float4*)&x[i * 8];
        float4 b = *(const float4*)&x[i * 8 + 4];
        short8 v;
        v[0] = (short)f2bf(a.x); v[1] = (short)f2bf(a.y);
        v[2] = (short)f2bf(a.z); v[3] = (short)f2bf(a.w);
        v[4] = (short)f2bf(b.x); v[5] = (short)f2bf(b.y);
        v[6] = (short)f2bf(b.z); v[7] = (short)f2bf(b.w);
        *(short8*)&xb[i * 8] = v;
        return;
    }
    const int widx = bid - 2048;
    const int z = widx >> 8, rem = widx & 255;
    const float* W = z == 0 ? W0 : z == 1 ? W1 : z == 2 ? W2 : W3;
    ushortT* T = z == 0 ? T0 : z == 1 ? T1 : z == 2 ? T2 : T3;
    const int kb = (rem >> 4) * 64, nb = (rem & 15) * 64;
#pragma unroll
    for (int it = 0; it < 4; it++) {
        int chunk = it * 256 + tid;
        int r = chunk >> 4, c4 = (chunk & 15) * 4;
        *(float4*)&tile[r][c4] = *(const float4*)&W[(size_t)(kb + r) * DIM + nb + c4];
    }
    __syncthreads();
#pragma unroll
    for (int it = 0; it < 2; it++) {
        int chunk = it * 256 + tid;
        int n = chunk >> 3, k8 = (chunk & 7) * 8;
        short8 o;
#pragma unroll
        for (int j = 0; j < 8; j++) o[j] = (short)f2bf(tile[k8 + j][n]);
        *(short8*)&T[(size_t)(nb + n) * DIM + kb + k8] = o;
    }
}

// ---------------------------------------------------------------------------
// Fused QKV GEMM, 16-wave (1024 thr) 256x256 tile, BK=64. R13 structure
// (measured 39.2 us) with ONE barrier per K-tile (was 2): k-half-1 reads
// need no barrier (buffer fully staged before the head barrier), and
// overwrite safety only needs the head rendezvous. 16 barrier rounds.
// vmcnt(0) at head drains the 4 next-tile loads issued ~1 full phase ago.
// ---------------------------------------------------------------------------
__global__ __launch_bounds__(1024, 4) void gemm_qkv8(const ushortT* __restrict__ A,
                                                     const ushortT* __restrict__ Bt,
                                                     const float* __restrict__ bq,
                                                     const float* __restrict__ bk,
                                                     const float* __restrict__ bv,
                                                     const float* __restrict__ ascale,
                                                     ushortT* __restrict__ Qb,
                                                     ushortT* __restrict__ Kb,
                                                     ushortT* __restrict__ VF) {
    __shared__ __align__(16) ushortT lds[65536];  // 128 KiB
    const int tid = threadIdx.x;
    const int lane = tid & 63, wid = tid >> 6;    // 16 waves
    const int wm = wid >> 2, wn = wid & 3;        // 4 x 4 waves, tile 64x64
    const int lo = lane & 15, hi = lane >> 4;
    const int bid = blockIdx.x;
    const int swz = (bid & 7) * 24 + (bid >> 3);  // XCD-bijective (192 % 8 == 0)
    const int bx = swz % 12, by = swz / 12;
    const int row0 = by * 256, col0 = bx * 256;
    const int srow = tid >> 2, sc = tid & 3;      // 1024 thr cover [256][4 chunks]
    f32x4 acc[4][4] = {};
    short8 af[4], bfr[4];

    auto stage = [&](int isA, int buf, int ksh, int kt) {
        const ushortT* g = isA ? A : Bt;
        int r0 = isA ? row0 : col0;
        int base = (isA ? 0 : 32768) + (buf * 2 + ksh) * 8192;
        int gch = sc ^ ((srow >> 1) & 3);
        gld16(&g[(size_t)(r0 + srow) * DIM + kt * 64 + ksh * 32 + gch * 8],
              &lds[base + tid * 8]);
    };
    auto loadA = [&](int buf, int ks) {
        int base = (buf * 2 + ks) * 8192;
#pragma unroll
        for (int mm = 0; mm < 4; mm++) {
            int row = wm * 64 + mm * 16 + lo;
            af[mm] = *(const short8*)&lds[base + row * 32 + (hi ^ ((row >> 1) & 3)) * 8];
        }
    };
    auto loadB = [&](int buf, int ks) {
        int base = 32768 + (buf * 2 + ks) * 8192;
#pragma unroll
        for (int n = 0; n < 4; n++) {
            int row = wn * 64 + n * 16 + lo;
            bfr[n] = *(const short8*)&lds[base + row * 32 + (hi ^ ((row >> 1) & 3)) * 8];
        }
    };
    auto mfma16 = [&]() {
        __builtin_amdgcn_s_setprio(1);
#pragma unroll
        for (int mm = 0; mm < 4; mm++)
#pragma unroll
            for (int n = 0; n < 4; n++)
                acc[mm][n] = __builtin_amdgcn_mfma_f32_16x16x32_bf16(
                    af[mm], bfr[n], acc[mm][n], 0, 0, 0);
        __builtin_amdgcn_s_setprio(0);
    };

    // prologue: tile 0, both k-halves (4 loads/thread outstanding)
    stage(0, 0, 0, 0); stage(1, 0, 0, 0);
    stage(0, 0, 1, 0); stage(1, 0, 1, 0);

#pragma unroll 1
    for (int t = 0; t < 16; ++t) {
        const int cur = t & 1, nxt = cur ^ 1;
        const bool more = (t < 15);
        asm volatile("s_waitcnt vmcnt(0)" ::: "memory");
        asm volatile("s_barrier" ::: "memory");
        // k-half 0
        loadA(cur, 0); loadB(cur, 0);
        if (more) { stage(0, nxt, 0, t + 1); stage(1, nxt, 0, t + 1); }
        mfma16();
        // k-half 1 (no barrier needed: cur buffer fully resident since head)
        loadA(cur, 1); loadB(cur, 1);
        if (more) { stage(0, nxt, 1, t + 1); stage(1, nxt, 1, t + 1); }
        mfma16();
    }
    __syncthreads();  // staging LDS now dead

    // ---- epilogue: wave tile = 64 tokens x 64 d (one head slab) ----
    const int cg = col0 + wn * 64;
    const int which = cg >> 10;  // 0=Q 1=K 2=V (tile never straddles)
    const int cwin = cg & 1023;
    const int h = cwin >> 6;
    const int t0g = row0 + wm * 64;
    const int b = t0g >> 11, tok0 = t0g & (SLEN - 1);
    const float* bias = which == 0 ? bq : which == 1 ? bk : bv;

    float bb4[4];
#pragma unroll
    for (int n = 0; n < 4; n++) bb4[n] = bias[cwin + n * 16 + lo];
#pragma unroll
    for (int m = 0; m < 4; m++)
#pragma unroll
        for (int n = 0; n < 4; n++)
#pragma unroll
            for (int r = 0; r < 4; r++) acc[m][n][r] += bb4[n];

    if (which < 2) {  // fused L2 norm over the 64-wide head row
        float asc = (which == 0) ? ascale[0] * LOG2E : 1.0f;
#pragma unroll
        for (int m = 0; m < 4; m++)
#pragma unroll
            for (int r = 0; r < 4; r++) {
                float ss = acc[m][0][r] * acc[m][0][r] + acc[m][1][r] * acc[m][1][r] +
                           acc[m][2][r] * acc[m][2][r] + acc[m][3][r] * acc[m][3][r];
#pragma unroll
                for (int o = 8; o > 0; o >>= 1) ss += __shfl_xor(ss, o);
                float sc2 = asc / fmaxf(sqrtf(ss), 1e-12f);
#pragma unroll
                for (int n = 0; n < 4; n++) acc[m][n][r] *= sc2;
            }
    }

    ushortT* tl = &lds[wid * 4096];  // wave-private 8KB bounce ([64][64] bf16)
    if (which < 2) {
#pragma unroll
        for (int m = 0; m < 4; m++)
#pragma unroll
            for (int n = 0; n < 4; n++)
#pragma unroll
                for (int r = 0; r < 4; r++) {
                    int row = m * 16 + 4 * hi + r;
                    int c = n * 2 + (lo >> 3);
                    tl[row * 64 + ((c ^ (row & 7)) << 3) + (lo & 7)] = f2bf(acc[m][n][r]);
                }
        ushortT* op = which == 0 ? Qb : Kb;
        const size_t base = ((size_t)(b * NH + h) * SLEN + tok0) * DPH;
#pragma unroll
        for (int j = 0; j < 8; j++) {
            int cid = j * 64 + lane;  // 512 16B chunks: row-major [64][8]
            int rowL = cid >> 3, c = cid & 7;
            uint4 v = *(const uint4*)&tl[rowL * 64 + ((c ^ (rowL & 7)) << 3)];
            *(uint4*)&op[base + (size_t)cid * 8] = v;
        }
    } else {
#pragma unroll
        for (int m = 0; m < 4; m++)
#pragma unroll
            for (int n = 0; n < 4; n++)
#pragma unroll
                for (int r = 0; r < 4; r++) {
                    int row = m * 16 + 4 * hi + r;
                    int c = n * 2 + (lo >> 3);
                    tl[row * 64 + ((c ^ ((row >> 3) & 7)) << 3) + (lo & 7)] = f2bf(acc[m][n][r]);
                }
        const int bh = b * NH + h;
        const int kt = tok0 >> 6;  // wave covers exactly one key tile
#pragma unroll
        for (int c2i = 0; c2i < 8; c2i++) {
            int jd = c2i >> 1, ks2 = c2i & 1;
            int colL = jd * 16 + lo;
            int cc2 = colL >> 3;
            short8 v;
#pragma unroll
            for (int e = 0; e < 8; e++) {
                int rowL = ks2 * 32 + 8 * hi + e;
                v[e] = (short)tl[rowL * 64 + ((cc2 ^ ((rowL >> 3) & 7)) << 3) + (colL & 7)];
            }
            *(short8*)&VF[((size_t)bh * 32 + kt) * 4096 + (size_t)(c2i * 64 + lane) * 8] = v;
        }
    }
}

// ---------------------------------------------------------------------------
// O-projection: out = ctx(4096,1024)bf16 @ Wo^T + bo, fp32 out.
// 512 thr / 8 waves, 128x128 tile, half-slot ring, vmcnt(4) steady,
// tail 2/0. LDS 64 KB -> 2 blocks/CU. Grid 256, XCD-swizzled. (R11)
// ---------------------------------------------------------------------------
__global__ __launch_bounds__(512, 2) void gemm_oproj(const ushortT* __restrict__ A,
                                                     const ushortT* __restrict__ Bt,
                                                     const float* __restrict__ bias,
                                                     float* __restrict__ outF) {
    __shared__ __align__(16) ushortT lds[32768];  // 64 KiB
    const int tid = threadIdx.x;
    const int lane = tid & 63, wid = tid >> 6;
    const int wm = wid >> 2, wn = wid & 3;  // 2 x 4 waves; wave tile 64 x 32
    const int lo = lane & 15, hi = lane >> 4;
    const int bid = blockIdx.x;
    const int swz = (bid & 7) * 32 + (bid >> 3);  // 256 % 8 == 0
    const int bx = swz & 7, by = swz >> 3;
    const int row0 = by * 128, col0 = bx * 128;
    const int srow = tid >> 2, sc = tid & 3;
    f32x4 acc[4][2] = {};
    short8 afO[2], bfO[2];

    auto stage = [&](int isA, int buf, int ksh, int kt) {
        const ushortT* g = isA ? A : Bt;
        int r0 = isA ? row0 : col0;
        int base = (isA ? 0 : 16384) + (buf * 2 + ksh) * 4096;
        int gch = sc ^ ((srow >> 1) & 3);
        gld16(&g[(size_t)(r0 + srow) * DIM + kt * 64 + ksh * 32 + gch * 8],
              &lds[base + tid * 8]);
    };
    auto loadAO = [&](int buf, int ks, int mh) {
        int base = (buf * 2 + ks) * 4096;
#pragma unroll
        for (int mm = 0; mm < 2; mm++) {
            int row = wm * 64 + (mh * 2 + mm) * 16 + lo;
            afO[mm] = *(const short8*)&lds[base + row * 32 + (hi ^ ((row >> 1) & 3)) * 8];
        }
    };
    auto loadBO = [&](int buf, int ks) {
        int base = 16384 + (buf * 2 + ks) * 4096;
#pragma unroll
        for (int n = 0; n < 2; n++) {
            int row = wn * 32 + n * 16 + lo;
            bfO[n] = *(const short8*)&lds[base + row * 32 + (hi ^ ((row >> 1) & 3)) * 8];
        }
    };
    auto mfma4 = [&](int mh) {
        __builtin_amdgcn_s_setprio(1);
#pragma unroll
        for (int mm = 0; mm < 2; mm++)
#pragma unroll
            for (int n = 0; n < 2; n++)
                acc[mh * 2 + mm][n] = __builtin_amdgcn_mfma_f32_16x16x32_bf16(
                    afO[mm], bfO[n], acc[mh * 2 + mm][n], 0, 0, 0);
        __builtin_amdgcn_s_setprio(0);
    };

    stage(1, 0, 0, 0); stage(0, 0, 0, 0);
    stage(1, 0, 1, 0); stage(0, 0, 1, 0);
    stage(1, 1, 0, 1); stage(0, 1, 0, 1);

#pragma unroll 1
    for (int it = 0; it < 8; ++it) {
        const int o = it * 2 + 1;
        const bool more = (it < 7);
        asm volatile("s_waitcnt vmcnt(4)" ::: "memory");
        asm volatile("s_barrier" ::: "memory");
        loadAO(0, 0, 0); loadBO(0, 0);
        stage(1, 1, 1, o);
        mfma4(0);
        asm volatile("s_barrier" ::: "memory");
        loadAO(0, 0, 1);
        stage(0, 1, 1, o);
        mfma4(1);
        asm volatile("s_waitcnt vmcnt(4)" ::: "memory");
        asm volatile("s_barrier" ::: "memory");
        loadAO(0, 1, 0); loadBO(0, 1);
        if (more) stage(1, 0, 0, o + 1);
        mfma4(0);
        asm volatile("s_barrier" ::: "memory");
        loadAO(0, 1, 1);
        if (more) stage(0, 0, 0, o + 1);
        mfma4(1);
        if (more) { asm volatile("s_waitcnt vmcnt(4)" ::: "memory"); }
        else      { asm volatile("s_waitcnt vmcnt(2)" ::: "memory"); }
        asm volatile("s_barrier" ::: "memory");
        loadAO(1, 0, 0); loadBO(1, 0);
        if (more) stage(1, 0, 1, o + 1);
        mfma4(0);
        asm volatile("s_barrier" ::: "memory");
        loadAO(1, 0, 1);
        if (more) stage(0, 0, 1, o + 1);
        mfma4(1);
        if (more) { asm volatile("s_waitcnt vmcnt(4)" ::: "memory"); }
        else      { asm volatile("s_waitcnt vmcnt(0)" ::: "memory"); }
        asm volatile("s_barrier" ::: "memory");
        loadAO(1, 1, 0); loadBO(1, 1);
        if (more) stage(1, 1, 0, o + 2);
        mfma4(0);
        asm volatile("s_barrier" ::: "memory");
        loadAO(1, 1, 1);
        if (more) stage(0, 1, 0, o + 2);
        mfma4(1);
    }
    __syncthreads();  // staging LDS dead

    float bb[2];
#pragma unroll
    for (int n = 0; n < 2; n++) bb[n] = bias[col0 + wn * 32 + n * 16 + lo];
#pragma unroll
    for (int m = 0; m < 4; m++)
#pragma unroll
        for (int n = 0; n < 2; n++)
#pragma unroll
            for (int r = 0; r < 4; r++) acc[m][n][r] += bb[n];

    float* tl = (float*)&lds[wid * 4096];  // wave-private [64][32] fp32, 8KB
#pragma unroll
    for (int m = 0; m < 4; m++)
#pragma unroll
        for (int n = 0; n < 2; n++)
#pragma unroll
            for (int r = 0; r < 4; r++) {
                int row = m * 16 + hi * 4 + r;
                int col = n * 16 + lo;
                int cc = col >> 2;
                tl[row * 32 + ((cc ^ (row & 7)) << 2) + (col & 3)] = acc[m][n][r];
            }
#pragma unroll
    for (int j = 0; j < 8; j++) {
        int cid = j * 64 + lane;  // 512 16B chunks: [64 rows][8 cc]
        int rowR = cid >> 3, cc = cid & 7;
        f32x4 v = *(const f32x4*)&tl[rowR * 32 + ((cc ^ (rowR & 7)) << 2)];
        int rg = row0 + wm * 64 + rowR;
        int cgl = col0 + wn * 32 + cc * 4;
        *(f32x4*)&outF[(size_t)rg * DIM + cgl] = v;
    }
}

// ---------------------------------------------------------------------------
// Causal flash attention, swapped-QK^T, exact fixed-shift exp2 softmax.
// R11 version: Ks double-buffered (one barrier per key tile), cvt_pk P->bf16,
// setprio around MFMA clusters. LDS 32 KB.
// ---------------------------------------------------------------------------
__global__ __launch_bounds__(512, 4) void attn(const ushortT* __restrict__ Q,
                                               const ushortT* __restrict__ K,
                                               const ushortT* __restrict__ VF,
                                               const float* __restrict__ scale,
                                               ushortT* __restrict__ ctx) {
    __shared__ __align__(16) ushortT Ks[2][64 * 64];
    __shared__ __align__(16) ushortT Ps[8 * 16 * 64];
    const int tid = threadIdx.x, lane = tid & 63, wid = tid >> 6;
    const int wg = wid & 3, sg = wid >> 2;
    const int bh = blockIdx.x, p = blockIdx.y;
    const int qt = sg ? p : 31 - p;
    const int kbmax = 31 - p;
    const size_t hb = (size_t)bh * SLEN * DPH;
    const int lo = lane & 15, hi = lane >> 4;
    const float mshift = fabsf(scale[0]) * LOG2E;

    short8 aq[2];
    {
        const int qrow = qt * 64 + wg * 16 + lo;
#pragma unroll
        for (int ks = 0; ks < 2; ks++)
            aq[ks] = *(const short8*)&Q[hb + (size_t)qrow * DPH + ks * 32 + 8 * hi];
    }

    const int srow = tid >> 3, sslot = tid & 7;
    const int sldsoff = srow * 64 + ((sslot ^ (srow & 7)) << 3);
    uint4 kr = *(const uint4*)&K[hb + (size_t)srow * DPH + sslot * 8];
    *(uint4*)&Ks[0][sldsoff] = kr;
    __syncthreads();

    f32x4 accd[4] = {};
    float lp = 0.f;

    for (int kb = 0; kb <= kbmax; kb++) {
        const int cur = kb & 1;
        if (kb < kbmax)
            kr = *(const uint4*)&K[hb + (size_t)((kb + 1) * 64 + srow) * DPH + sslot * 8];

        if (kb <= qt) {
            short8 bv[8];
            const ushortT* vt = &VF[(((size_t)bh * 32 + kb) * 512 + lane) * 8];
#pragma unroll
            for (int c = 0; c < 8; c++) bv[c] = *(const short8*)&vt[(size_t)c * 512];

            f32x4 sf[4] = {};
            __builtin_amdgcn_s_setprio(1);
#pragma unroll
            for (int ks = 0; ks < 2; ks++)
#pragma unroll
                for (int j = 0; j < 4; j++) {
                    int row = j * 16 + lo;
                    short8 bk = *(const short8*)&Ks[cur][row * 64 + (((ks * 4 + hi) ^ (row & 7)) << 3)];
                    sf[j] = __builtin_amdgcn_mfma_f32_16x16x32_bf16(bk, aq[ks], sf[j], 0, 0, 0);
                }
            __builtin_amdgcn_s_setprio(0);

            if (kb == qt) {
#pragma unroll
                for (int j = 0; j < 4; j++)
#pragma unroll
                    for (int r = 0; r < 4; r++)
                        if (j * 16 + 4 * hi + r > wg * 16 + lo) sf[j][r] = -INFINITY;
            }

#pragma unroll
            for (int j = 0; j < 4; j++) {
                float pv0 = __builtin_amdgcn_exp2f(sf[j][0] - mshift);
                float pv1 = __builtin_amdgcn_exp2f(sf[j][1] - mshift);
                float pv2 = __builtin_amdgcn_exp2f(sf[j][2] - mshift);
                float pv3 = __builtin_amdgcn_exp2f(sf[j][3] - mshift);
                lp += (pv0 + pv1) + (pv2 + pv3);
                uint2 pk;
                pk.x = cvtpk_bf16(pv0, pv1);
                pk.y = cvtpk_bf16(pv2, pv3);
                int slot = (4 * j + hi) ^ (2 * (lo & 7));
                *(uint2*)&Ps[wid * 1024 + lo * 64 + slot * 4] = pk;
            }

            __builtin_amdgcn_s_setprio(1);
#pragma unroll
            for (int ks = 0; ks < 2; ks++) {
                int slot0 = (8 * ks + 2 * hi) ^ (2 * (lo & 7));
                short8 ap = *(const short8*)&Ps[wid * 1024 + lo * 64 + slot0 * 4];
#pragma unroll
                for (int jd = 0; jd < 4; jd++)
                    accd[jd] = __builtin_amdgcn_mfma_f32_16x16x32_bf16(ap, bv[jd * 2 + ks], accd[jd], 0, 0, 0);
            }
            __builtin_amdgcn_s_setprio(0);
        }

        if (kb < kbmax) *(uint4*)&Ks[cur ^ 1][sldsoff] = kr;
        __syncthreads();  // one barrier per tile: next tile's buffer ready
    }

    lp += __shfl_xor(lp, 16);
    lp += __shfl_xor(lp, 32);

    const int b = bh >> 4, h = bh & 15;
#pragma unroll
    for (int r = 0; r < 4; r++) {
        float lr = __shfl(lp, (lane & 48) | (4 * hi + r));
        float inv = 1.0f / lr;
        int t = qt * 64 + wg * 16 + 4 * hi + r;
#pragma unroll
        for (int jd = 0; jd < 4; jd++) {
            int d = jd * 16 + lo;
            ctx[(size_t)(b * SLEN + t) * DIM + h * 64 + d] = f2bf(accd[jd][r] * inv);
        }
    }
}

// ---------------------------------------------------------------------------
// inputs: 0 x, 1 mask(unused), 2 Wq, 3 bq, 4 Wk, 5 bk, 6 Wv, 7 bv, 8 Wo,
// 9 bo, 10 attention_scale
// ---------------------------------------------------------------------------
extern "C" void kernel_launch(void* const* d_in, const int* in_sizes, int n_in,
                              void* d_out, int out_size, void* d_ws,
                              size_t ws_size, hipStream_t stream) {
    const float* x = (const float*)d_in[0];
    const float* Wq = (const float*)d_in[2];
    const float* bq = (const float*)d_in[3];
    const float* Wk = (const float*)d_in[4];
    const float* bk = (const float*)d_in[5];
    const float* Wv = (const float*)d_in[6];
    const float* bv = (const float*)d_in[7];
    const float* Wo = (const float*)d_in[8];
    const float* bo = (const float*)d_in[9];
    const float* ascale = (const float*)d_in[10];
    float* outF = (float*)d_out;

    unsigned char* ws = (unsigned char*)d_ws;
    const size_t MB = 1u << 20;
    ushortT* xb = (ushortT*)(ws);               // 8 MB
    ushortT* Wqkvt = (ushortT*)(ws + 8 * MB);   // 6 MB
    ushortT* Wot = (ushortT*)(ws + 14 * MB);    // 2 MB
    ushortT* Qb = (ushortT*)(ws + 16 * MB);     // 8 MB
    ushortT* Kb = (ushortT*)(ws + 24 * MB);     // 8 MB
    ushortT* VFb = (ushortT*)(ws + 32 * MB);    // 8 MB
    ushortT* ctxb = (ushortT*)(ws + 40 * MB);   // 8 MB; total 48 MB

    cvt_all<<<3072, 256, 0, stream>>>(x, xb, Wq, Wk, Wv, Wo, Wqkvt,
                                      Wqkvt + (size_t)1024 * 1024,
                                      Wqkvt + (size_t)2048 * 1024, Wot);

    gemm_qkv8<<<dim3(192), 1024, 0, stream>>>(xb, Wqkvt, bq, bk, bv, ascale, Qb, Kb, VFb);

    attn<<<dim3(32, 16), 512, 0, stream>>>(Qb, Kb, VFb, ascale, ctxb);

    gemm_oproj<<<dim3(256), 512, 0, stream>>>(ctxb, Wot, bo, outF);
}